// Round 3
// baseline (27.086 us; speedup 1.0000x reference)
//
#include <hip/hip_runtime.h>

#define NQ 20

typedef float v2f __attribute__((ext_vector_type(2)));

static __device__ __forceinline__ v2f b2(float s) { return (v2f){s, s}; }
static __device__ __forceinline__ v2f fma2(v2f a, v2f b, v2f c) { return __builtin_elementwise_fma(a, b, c); }
static __device__ __forceinline__ v2f fmab(v2f a, float b, v2f c) { return __builtin_elementwise_fma(a, b2(b), c); }
static __device__ __forceinline__ v2f relu2(v2f a) { return __builtin_elementwise_max(a, b2(0.0f)); }

// 2 rows per thread, all row math in v2f -> v_pk_*_f32 (one packed op each).
// q-loop fully unrolled; per-q state recomputed from q (no value+slope pairs)
// to keep VGPR <= 64 so 8 waves/SIMD fit (__launch_bounds__(256, 8)).
__global__ __launch_bounds__(256, 8) void monotone_v2pk(
    const float4* __restrict__ x4,
    const float* __restrict__ p_m0_wd, const float* __restrict__ p_m0_ws1,
    const float* __restrict__ p_m0_bs1, const float* __restrict__ p_m0_wl,
    const float* __restrict__ p_m0_bl,
    const float* __restrict__ p_m1_wd, const float* __restrict__ p_m1_ws0,
    const float* __restrict__ p_m1_bs0, const float* __restrict__ p_m1_ws1,
    const float* __restrict__ p_m1_bs1, const float* __restrict__ p_m1_wl,
    const float* __restrict__ p_m1_bl,
    const float* __restrict__ p_g0_b,
    const float* __restrict__ p_g1_ws0, const float* __restrict__ p_g1_bs0,
    const float* __restrict__ p_g1_ws1, const float* __restrict__ p_g1_bs1,
    const float* __restrict__ p_g1_wl, const float* __restrict__ p_g1_bl,
    float4* __restrict__ out4, int T)
{
    const int t = blockIdx.x * blockDim.x + threadIdx.x;
    if (t >= T) return;

    const float step = 1.0f / (float)NQ;

    // ---- uniform weights (uniform addresses -> scalar loads / SGPRs) ----
    float m0_wd[4], m0_ws1[16], m0_bs1[4], m0_wl[4], m0_bl;
    float m1_wd[4], m1_ws0[4], m1_bs0[4], m1_ws1[16], m1_bs1[4], m1_wl[4], m1_bl;
    float g0b;
    float g1_ws0[8], g1_bs0[4], g1_ws1[16], g1_bs1[4], g1_wl[4], g1_bl;

#pragma unroll
    for (int i = 0; i < 4; ++i) {
        m0_wd[i] = p_m0_wd[i];  m0_bs1[i] = p_m0_bs1[i];  m0_wl[i] = p_m0_wl[i];
        m1_wd[i] = p_m1_wd[i];  m1_ws0[i] = p_m1_ws0[i];  m1_bs0[i] = p_m1_bs0[i];
        m1_bs1[i] = p_m1_bs1[i]; m1_wl[i] = p_m1_wl[i];
        g1_bs0[i] = p_g1_bs0[i]; g1_bs1[i] = p_g1_bs1[i]; g1_wl[i] = p_g1_wl[i];
    }
#pragma unroll
    for (int i = 0; i < 16; ++i) { m0_ws1[i] = p_m0_ws1[i]; m1_ws1[i] = p_m1_ws1[i]; g1_ws1[i] = p_g1_ws1[i]; }
#pragma unroll
    for (int i = 0; i < 8; ++i) g1_ws0[i] = p_g1_ws0[i];
    m0_bl = p_m0_bl[0]; m1_bl = p_m1_bl[0]; g0b = p_g0_b[0]; g1_bl = p_g1_bl[0];

    // ---- load 2 rows ----
    const float4 a = x4[t];
    v2f x0 = {a.x, a.z};
    v2f x1 = {a.y, a.w};

    // ---- gen MLP (2-4-4-1) on [x0,x1] ----
    v2f g;
    {
        v2f h0[4];
#pragma unroll
        for (int j = 0; j < 4; ++j)
            h0[j] = relu2(fmab(x1, g1_ws0[4 + j], fmab(x0, g1_ws0[j], b2(g1_bs0[j]))));
        v2f f = b2(g1_bl);
#pragma unroll
        for (int k = 0; k < 4; ++k) {
            v2f v = b2(g1_bs1[k]);
#pragma unroll
            for (int j = 0; j < 4; ++j) v = fmab(h0[j], g1_ws1[j * 4 + k], v);
            f = fmab(relu2(v), g1_wl[k], f);
        }
        g = f;
    }

    // ---- head 0 precompute (temp==0): h0 = q*relu(x0*wd) => preact = q*c_k + bs1_k ----
    v2f c[4] = {b2(0.f), b2(0.f), b2(0.f), b2(0.f)};
#pragma unroll
    for (int h = 0; h < 4; ++h) {
        v2f rb = relu2(x0 * b2(m0_wd[h]));
#pragma unroll
        for (int k = 0; k < 4; ++k) c[k] = fmab(rb, m0_ws1[h * 4 + k], c[k]);
    }

    // ---- head 1 precompute: u_h(q) = q*s1_h + t_h ----
    v2f s1[4], tt[4];
#pragma unroll
    for (int h = 0; h < 4; ++h) {
        s1[h] = x1 * b2(m1_wd[h]);
        tt[h] = fmab(x0, m1_ws0[h], b2(m1_bs0[h]));
    }

    // ---- merged quadrature loop ----
    v2f acc0 = b2(0.f), acc1 = b2(0.f);
#pragma unroll
    for (int qi = 0; qi < NQ; ++qi) {
        const float q = (float)qi * step;

        // head 0
        v2f f0 = b2(m0_bl);
#pragma unroll
        for (int k = 0; k < 4; ++k) {
            v2f v = relu2(fmab(c[k], q, b2(m0_bs1[k])));
            f0 = fmab(v, m0_wl[k], f0);
        }
        acc0 = fma2(f0, f0, acc0);

        // head 1
        v2f h0[4];
#pragma unroll
        for (int h = 0; h < 4; ++h) h0[h] = relu2(fmab(s1[h], q, tt[h]));
        v2f f1 = b2(m1_bl);
#pragma unroll
        for (int k = 0; k < 4; ++k) {
            v2f vv = b2(m1_bs1[k]);
#pragma unroll
            for (int h = 0; h < 4; ++h) vv = fmab(h0[h], m1_ws1[h * 4 + k], vv);
            f1 = fmab(relu2(vv), m1_wl[k], f1);
        }
        acc1 = fma2(f1, f1, acc1);
    }

    v2f y0 = (acc0 * b2(step)) * x0 + b2(g0b);
    v2f y1 = fma2(acc1 * b2(step), x1, g);

    const float4 o = {y0.x, y1.x, y0.y, y1.y};
    out4[t] = o;
}

extern "C" void kernel_launch(void* const* d_in, const int* in_sizes, int n_in,
                              void* d_out, int out_size, void* d_ws, size_t ws_size,
                              hipStream_t stream) {
    const float* x       = (const float*)d_in[0];
    const float* m0_wd   = (const float*)d_in[1];
    const float* m0_ws1  = (const float*)d_in[2];
    const float* m0_bs1  = (const float*)d_in[3];
    const float* m0_wl   = (const float*)d_in[4];
    const float* m0_bl   = (const float*)d_in[5];
    const float* m1_wd   = (const float*)d_in[6];
    const float* m1_ws0  = (const float*)d_in[7];
    const float* m1_bs0  = (const float*)d_in[8];
    const float* m1_ws1  = (const float*)d_in[9];
    const float* m1_bs1  = (const float*)d_in[10];
    const float* m1_wl   = (const float*)d_in[11];
    const float* m1_bl   = (const float*)d_in[12];
    const float* g0_b    = (const float*)d_in[13];
    const float* g1_ws0  = (const float*)d_in[14];
    const float* g1_bs0  = (const float*)d_in[15];
    const float* g1_ws1  = (const float*)d_in[16];
    const float* g1_bs1  = (const float*)d_in[17];
    const float* g1_wl   = (const float*)d_in[18];
    const float* g1_bl   = (const float*)d_in[19];
    float* out = (float*)d_out;

    const int nrows = in_sizes[0] / 2;   // 1048576 (even)
    const int T     = nrows / 2;         // 2 rows per thread
    const int threads = 256;
    const int blocks  = (T + threads - 1) / threads;

    hipLaunchKernelGGL(monotone_v2pk, dim3(blocks), dim3(threads), 0, stream,
                       (const float4*)x, m0_wd, m0_ws1, m0_bs1, m0_wl, m0_bl,
                       m1_wd, m1_ws0, m1_bs0, m1_ws1, m1_bs1, m1_wl, m1_bl,
                       g0_b, g1_ws0, g1_bs0, g1_ws1, g1_bs1, g1_wl, g1_bl,
                       (float4*)out, T);
}

// Round 4
// 26.613 us; speedup vs baseline: 1.0178x; 1.0178x over previous
//
#include <hip/hip_runtime.h>

#define NQ 20

typedef float v2f __attribute__((ext_vector_type(2)));

static __device__ __forceinline__ v2f b2(float s) { return (v2f){s, s}; }
static __device__ __forceinline__ v2f fma2(v2f a, v2f b, v2f c) { return __builtin_elementwise_fma(a, b, c); }
static __device__ __forceinline__ v2f fmab(v2f a, float b, v2f c) { return __builtin_elementwise_fma(a, b2(b), c); }
static __device__ __forceinline__ v2f relu2(v2f a) { return __builtin_elementwise_max(a, b2(0.0f)); }

// 2 rows per thread in v2f (-> v_pk_*_f32). ROLLED q-loop (unroll 2) so the
// ~40 splatted weight constants are loop-invariant and stay in VGPRs (no
// remat/mov bloat), body ~<1KB (no I-fetch pressure). No min-wave clamp:
// let VGPR land ~110-130 (4 waves/SIMD was shown sufficient in r2 vs r3).
__global__ __launch_bounds__(256) void monotone_v2pk_rolled(
    const float4* __restrict__ x4,
    const float* __restrict__ p_m0_wd, const float* __restrict__ p_m0_ws1,
    const float* __restrict__ p_m0_bs1, const float* __restrict__ p_m0_wl,
    const float* __restrict__ p_m0_bl,
    const float* __restrict__ p_m1_wd, const float* __restrict__ p_m1_ws0,
    const float* __restrict__ p_m1_bs0, const float* __restrict__ p_m1_ws1,
    const float* __restrict__ p_m1_bs1, const float* __restrict__ p_m1_wl,
    const float* __restrict__ p_m1_bl,
    const float* __restrict__ p_g0_b,
    const float* __restrict__ p_g1_ws0, const float* __restrict__ p_g1_bs0,
    const float* __restrict__ p_g1_ws1, const float* __restrict__ p_g1_bs1,
    const float* __restrict__ p_g1_wl, const float* __restrict__ p_g1_bl,
    float4* __restrict__ out4, int T)
{
    const int t = blockIdx.x * blockDim.x + threadIdx.x;
    if (t >= T) return;

    const float step = 1.0f / (float)NQ;

    // ---- uniform weights ----
    float m0_wd[4], m0_ws1[16], m0_bs1[4], m0_wl[4], m0_bl;
    float m1_wd[4], m1_ws0[4], m1_bs0[4], m1_ws1[16], m1_bs1[4], m1_wl[4], m1_bl;
    float g0b;
    float g1_ws0[8], g1_bs0[4], g1_ws1[16], g1_bs1[4], g1_wl[4], g1_bl;

#pragma unroll
    for (int i = 0; i < 4; ++i) {
        m0_wd[i] = p_m0_wd[i];  m0_bs1[i] = p_m0_bs1[i];  m0_wl[i] = p_m0_wl[i];
        m1_wd[i] = p_m1_wd[i];  m1_ws0[i] = p_m1_ws0[i];  m1_bs0[i] = p_m1_bs0[i];
        m1_bs1[i] = p_m1_bs1[i]; m1_wl[i] = p_m1_wl[i];
        g1_bs0[i] = p_g1_bs0[i]; g1_bs1[i] = p_g1_bs1[i]; g1_wl[i] = p_g1_wl[i];
    }
#pragma unroll
    for (int i = 0; i < 16; ++i) { m0_ws1[i] = p_m0_ws1[i]; m1_ws1[i] = p_m1_ws1[i]; g1_ws1[i] = p_g1_ws1[i]; }
#pragma unroll
    for (int i = 0; i < 8; ++i) g1_ws0[i] = p_g1_ws0[i];
    m0_bl = p_m0_bl[0]; m1_bl = p_m1_bl[0]; g0b = p_g0_b[0]; g1_bl = p_g1_bl[0];

    // ---- load 2 rows ----
    const float4 a = x4[t];
    v2f x0 = {a.x, a.z};
    v2f x1 = {a.y, a.w};

    // ---- gen MLP (2-4-4-1) ----
    v2f g;
    {
        v2f h0[4];
#pragma unroll
        for (int j = 0; j < 4; ++j)
            h0[j] = relu2(fmab(x1, g1_ws0[4 + j], fmab(x0, g1_ws0[j], b2(g1_bs0[j]))));
        v2f f = b2(g1_bl);
#pragma unroll
        for (int k = 0; k < 4; ++k) {
            v2f v = b2(g1_bs1[k]);
#pragma unroll
            for (int j = 0; j < 4; ++j) v = fmab(h0[j], g1_ws1[j * 4 + k], v);
            f = fmab(relu2(v), g1_wl[k], f);
        }
        g = f;
    }

    // ---- head 0 precompute (temp==0): preact_k(q) = q*c_k + bs1_k ----
    v2f c[4] = {b2(0.f), b2(0.f), b2(0.f), b2(0.f)};
#pragma unroll
    for (int h = 0; h < 4; ++h) {
        v2f rb = relu2(x0 * b2(m0_wd[h]));
#pragma unroll
        for (int k = 0; k < 4; ++k) c[k] = fmab(rb, m0_ws1[h * 4 + k], c[k]);
    }

    // ---- head 1 precompute: u_h(q) = q*s1_h + tt_h ----
    v2f s1[4], tt[4];
#pragma unroll
    for (int h = 0; h < 4; ++h) {
        s1[h] = x1 * b2(m1_wd[h]);
        tt[h] = fmab(x0, m1_ws0[h], b2(m1_bs0[h]));
    }

    // ---- merged quadrature loop (rolled; unroll 2 for ILP) ----
    v2f acc0 = b2(0.f), acc1 = b2(0.f);
    float q = 0.0f;
#pragma unroll 2
    for (int qi = 0; qi < NQ; ++qi) {
        // head 0
        v2f f0 = b2(m0_bl);
#pragma unroll
        for (int k = 0; k < 4; ++k) {
            v2f v = relu2(fmab(c[k], q, b2(m0_bs1[k])));
            f0 = fmab(v, m0_wl[k], f0);
        }
        acc0 = fma2(f0, f0, acc0);

        // head 1
        v2f h0[4];
#pragma unroll
        for (int h = 0; h < 4; ++h) h0[h] = relu2(fmab(s1[h], q, tt[h]));
        v2f f1 = b2(m1_bl);
#pragma unroll
        for (int k = 0; k < 4; ++k) {
            v2f vv = b2(m1_bs1[k]);
#pragma unroll
            for (int h = 0; h < 4; ++h) vv = fmab(h0[h], m1_ws1[h * 4 + k], vv);
            f1 = fmab(relu2(vv), m1_wl[k], f1);
        }
        acc1 = fma2(f1, f1, acc1);

        q += step;
    }

    v2f y0 = (acc0 * b2(step)) * x0 + b2(g0b);
    v2f y1 = fma2(acc1 * b2(step), x1, g);

    const float4 o = {y0.x, y1.x, y0.y, y1.y};
    out4[t] = o;
}

extern "C" void kernel_launch(void* const* d_in, const int* in_sizes, int n_in,
                              void* d_out, int out_size, void* d_ws, size_t ws_size,
                              hipStream_t stream) {
    const float* x       = (const float*)d_in[0];
    const float* m0_wd   = (const float*)d_in[1];
    const float* m0_ws1  = (const float*)d_in[2];
    const float* m0_bs1  = (const float*)d_in[3];
    const float* m0_wl   = (const float*)d_in[4];
    const float* m0_bl   = (const float*)d_in[5];
    const float* m1_wd   = (const float*)d_in[6];
    const float* m1_ws0  = (const float*)d_in[7];
    const float* m1_bs0  = (const float*)d_in[8];
    const float* m1_ws1  = (const float*)d_in[9];
    const float* m1_bs1  = (const float*)d_in[10];
    const float* m1_wl   = (const float*)d_in[11];
    const float* m1_bl   = (const float*)d_in[12];
    const float* g0_b    = (const float*)d_in[13];
    const float* g1_ws0  = (const float*)d_in[14];
    const float* g1_bs0  = (const float*)d_in[15];
    const float* g1_ws1  = (const float*)d_in[16];
    const float* g1_bs1  = (const float*)d_in[17];
    const float* g1_wl   = (const float*)d_in[18];
    const float* g1_bl   = (const float*)d_in[19];
    float* out = (float*)d_out;

    const int nrows = in_sizes[0] / 2;   // 1048576 (even)
    const int T     = nrows / 2;         // 2 rows per thread
    const int threads = 256;
    const int blocks  = (T + threads - 1) / threads;

    hipLaunchKernelGGL(monotone_v2pk_rolled, dim3(blocks), dim3(threads), 0, stream,
                       (const float4*)x, m0_wd, m0_ws1, m0_bs1, m0_wl, m0_bl,
                       m1_wd, m1_ws0, m1_bs0, m1_ws1, m1_bs1, m1_wl, m1_bl,
                       g0_b, g1_ws0, g1_bs0, g1_ws1, g1_bs1, g1_wl, g1_bl,
                       (float4*)out, T);
}

// Round 5
// 24.382 us; speedup vs baseline: 1.1109x; 1.0915x over previous
//
#include <hip/hip_runtime.h>

#define NQ 20

typedef float  v2f __attribute__((ext_vector_type(2)));
typedef _Float16 h2 __attribute__((ext_vector_type(2)));

static __device__ __forceinline__ v2f b2(float s) { return (v2f){s, s}; }
static __device__ __forceinline__ v2f fma2(v2f a, v2f b, v2f c) { return __builtin_elementwise_fma(a, b, c); }
static __device__ __forceinline__ v2f fmab(v2f a, float b, v2f c) { return __builtin_elementwise_fma(a, b2(b), c); }
static __device__ __forceinline__ v2f relu2(v2f a) { return __builtin_elementwise_max(a, b2(0.0f)); }

static __device__ __forceinline__ h2 bh(float s) { _Float16 h = (_Float16)s; return (h2){h, h}; }
static __device__ __forceinline__ h2 h2pack(v2f a) { return (h2){(_Float16)a.x, (_Float16)a.y}; }
static __device__ __forceinline__ h2 fmah(h2 a, h2 b, h2 c) { return __builtin_elementwise_fma(a, b, c); }
static __device__ __forceinline__ h2 reluh(h2 a) { return __builtin_elementwise_max(a, (h2){(_Float16)0.f, (_Float16)0.f}); }

// 2 rows/thread. Prologue (gen MLP, per-head affine precompute) in fp32.
// Quadrature loop in packed fp16 (v_pk_fma_f16 / v_pk_max_f16, full-rate RPM
// = 2x fp32 FLOP rate); f^2 accumulated in fp32 via fma(fpext,fpext,f32)
// -> v_fma_mix_f32 so the 20-term reduction keeps fp32 precision.
__global__ __launch_bounds__(256) void monotone_h2(
    const float4* __restrict__ x4,
    const float* __restrict__ p_m0_wd, const float* __restrict__ p_m0_ws1,
    const float* __restrict__ p_m0_bs1, const float* __restrict__ p_m0_wl,
    const float* __restrict__ p_m0_bl,
    const float* __restrict__ p_m1_wd, const float* __restrict__ p_m1_ws0,
    const float* __restrict__ p_m1_bs0, const float* __restrict__ p_m1_ws1,
    const float* __restrict__ p_m1_bs1, const float* __restrict__ p_m1_wl,
    const float* __restrict__ p_m1_bl,
    const float* __restrict__ p_g0_b,
    const float* __restrict__ p_g1_ws0, const float* __restrict__ p_g1_bs0,
    const float* __restrict__ p_g1_ws1, const float* __restrict__ p_g1_bs1,
    const float* __restrict__ p_g1_wl, const float* __restrict__ p_g1_bl,
    float4* __restrict__ out4, int T)
{
    const int t = blockIdx.x * blockDim.x + threadIdx.x;
    if (t >= T) return;

    const float step = 1.0f / (float)NQ;

    // ---- uniform weights (fp32) ----
    float m0_wd[4], m0_ws1[16], m0_bs1[4], m0_wl[4], m0_bl;
    float m1_wd[4], m1_ws0[4], m1_bs0[4], m1_ws1[16], m1_bs1[4], m1_wl[4], m1_bl;
    float g0b;
    float g1_ws0[8], g1_bs0[4], g1_ws1[16], g1_bs1[4], g1_wl[4], g1_bl;

#pragma unroll
    for (int i = 0; i < 4; ++i) {
        m0_wd[i] = p_m0_wd[i];  m0_bs1[i] = p_m0_bs1[i];  m0_wl[i] = p_m0_wl[i];
        m1_wd[i] = p_m1_wd[i];  m1_ws0[i] = p_m1_ws0[i];  m1_bs0[i] = p_m1_bs0[i];
        m1_bs1[i] = p_m1_bs1[i]; m1_wl[i] = p_m1_wl[i];
        g1_bs0[i] = p_g1_bs0[i]; g1_bs1[i] = p_g1_bs1[i]; g1_wl[i] = p_g1_wl[i];
    }
#pragma unroll
    for (int i = 0; i < 16; ++i) { m0_ws1[i] = p_m0_ws1[i]; m1_ws1[i] = p_m1_ws1[i]; g1_ws1[i] = p_g1_ws1[i]; }
#pragma unroll
    for (int i = 0; i < 8; ++i) g1_ws0[i] = p_g1_ws0[i];
    m0_bl = p_m0_bl[0]; m1_bl = p_m1_bl[0]; g0b = p_g0_b[0]; g1_bl = p_g1_bl[0];

    // ---- load 2 rows ----
    const float4 a = x4[t];
    v2f x0 = {a.x, a.z};
    v2f x1 = {a.y, a.w};

    // ---- gen MLP (2-4-4-1), fp32 ----
    v2f g;
    {
        v2f h0[4];
#pragma unroll
        for (int j = 0; j < 4; ++j)
            h0[j] = relu2(fmab(x1, g1_ws0[4 + j], fmab(x0, g1_ws0[j], b2(g1_bs0[j]))));
        v2f f = b2(g1_bl);
#pragma unroll
        for (int k = 0; k < 4; ++k) {
            v2f v = b2(g1_bs1[k]);
#pragma unroll
            for (int j = 0; j < 4; ++j) v = fmab(h0[j], g1_ws1[j * 4 + k], v);
            f = fmab(relu2(v), g1_wl[k], f);
        }
        g = f;
    }

    // ---- head 0 precompute (fp32): preact_k(q) = q*c_k + bs1_k ----
    v2f c[4] = {b2(0.f), b2(0.f), b2(0.f), b2(0.f)};
#pragma unroll
    for (int h = 0; h < 4; ++h) {
        v2f rb = relu2(x0 * b2(m0_wd[h]));
#pragma unroll
        for (int k = 0; k < 4; ++k) c[k] = fmab(rb, m0_ws1[h * 4 + k], c[k]);
    }

    // ---- head 1 precompute (fp32): u_h(q) = q*s1_h + tt_h ----
    v2f s1[4], tt[4];
#pragma unroll
    for (int h = 0; h < 4; ++h) {
        s1[h] = x1 * b2(m1_wd[h]);
        tt[h] = fmab(x0, m1_ws0[h], b2(m1_bs0[h]));
    }

    // ---- convert per-thread state + loop constants to packed fp16 ----
    h2 ch[4], sh[4], th[4];
#pragma unroll
    for (int k = 0; k < 4; ++k) { ch[k] = h2pack(c[k]); sh[k] = h2pack(s1[k]); th[k] = h2pack(tt[k]); }
    h2 m0_bs1h[4], m0_wlh[4], m1_ws1h[16], m1_bs1h[4], m1_wlh[4];
#pragma unroll
    for (int k = 0; k < 4; ++k) {
        m0_bs1h[k] = bh(m0_bs1[k]); m0_wlh[k] = bh(m0_wl[k]);
        m1_bs1h[k] = bh(m1_bs1[k]); m1_wlh[k] = bh(m1_wl[k]);
    }
#pragma unroll
    for (int i = 0; i < 16; ++i) m1_ws1h[i] = bh(m1_ws1[i]);
    const h2 m0_blh = bh(m0_bl);
    const h2 m1_blh = bh(m1_bl);

    // ---- quadrature loop: packed fp16, fp32 accumulation via fma_mix ----
    float acc0a = 0.f, acc0b = 0.f, acc1a = 0.f, acc1b = 0.f;
    float qf = 0.0f;
#pragma unroll 2
    for (int qi = 0; qi < NQ; ++qi) {
        const h2 qq = bh(qf);

        // head 0
        h2 f0 = m0_blh;
#pragma unroll
        for (int k = 0; k < 4; ++k) {
            h2 v = reluh(fmah(ch[k], qq, m0_bs1h[k]));
            f0 = fmah(v, m0_wlh[k], f0);
        }
        acc0a = fmaf((float)f0.x, (float)f0.x, acc0a);
        acc0b = fmaf((float)f0.y, (float)f0.y, acc0b);

        // head 1
        h2 hh[4];
#pragma unroll
        for (int h = 0; h < 4; ++h) hh[h] = reluh(fmah(sh[h], qq, th[h]));
        h2 f1 = m1_blh;
#pragma unroll
        for (int k = 0; k < 4; ++k) {
            h2 vv = fmah(hh[0], m1_ws1h[k], m1_bs1h[k]);
#pragma unroll
            for (int h = 1; h < 4; ++h) vv = fmah(hh[h], m1_ws1h[h * 4 + k], vv);
            f1 = fmah(reluh(vv), m1_wlh[k], f1);
        }
        acc1a = fmaf((float)f1.x, (float)f1.x, acc1a);
        acc1b = fmaf((float)f1.y, (float)f1.y, acc1b);

        qf += step;
    }

    v2f acc0 = {acc0a, acc0b};
    v2f acc1 = {acc1a, acc1b};
    v2f y0 = (acc0 * b2(step)) * x0 + b2(g0b);
    v2f y1 = fma2(acc1 * b2(step), x1, g);

    const float4 o = {y0.x, y1.x, y0.y, y1.y};
    out4[t] = o;
}

extern "C" void kernel_launch(void* const* d_in, const int* in_sizes, int n_in,
                              void* d_out, int out_size, void* d_ws, size_t ws_size,
                              hipStream_t stream) {
    const float* x       = (const float*)d_in[0];
    const float* m0_wd   = (const float*)d_in[1];
    const float* m0_ws1  = (const float*)d_in[2];
    const float* m0_bs1  = (const float*)d_in[3];
    const float* m0_wl   = (const float*)d_in[4];
    const float* m0_bl   = (const float*)d_in[5];
    const float* m1_wd   = (const float*)d_in[6];
    const float* m1_ws0  = (const float*)d_in[7];
    const float* m1_bs0  = (const float*)d_in[8];
    const float* m1_ws1  = (const float*)d_in[9];
    const float* m1_bs1  = (const float*)d_in[10];
    const float* m1_wl   = (const float*)d_in[11];
    const float* m1_bl   = (const float*)d_in[12];
    const float* g0_b    = (const float*)d_in[13];
    const float* g1_ws0  = (const float*)d_in[14];
    const float* g1_bs0  = (const float*)d_in[15];
    const float* g1_ws1  = (const float*)d_in[16];
    const float* g1_bs1  = (const float*)d_in[17];
    const float* g1_wl   = (const float*)d_in[18];
    const float* g1_bl   = (const float*)d_in[19];
    float* out = (float*)d_out;

    const int nrows = in_sizes[0] / 2;   // 1048576 (even)
    const int T     = nrows / 2;         // 2 rows per thread
    const int threads = 256;
    const int blocks  = (T + threads - 1) / threads;

    hipLaunchKernelGGL(monotone_h2, dim3(blocks), dim3(threads), 0, stream,
                       (const float4*)x, m0_wd, m0_ws1, m0_bs1, m0_wl, m0_bl,
                       m1_wd, m1_ws0, m1_bs0, m1_ws1, m1_bs1, m1_wl, m1_bl,
                       g0_b, g1_ws0, g1_bs0, g1_ws1, g1_bs1, g1_wl, g1_bl,
                       (float4*)out, T);
}

// Round 6
// 24.260 us; speedup vs baseline: 1.1165x; 1.0050x over previous
//
#include <hip/hip_runtime.h>

#define NQ 20

typedef float  v2f __attribute__((ext_vector_type(2)));
typedef _Float16 h2 __attribute__((ext_vector_type(2)));

static __device__ __forceinline__ v2f b2(float s) { return (v2f){s, s}; }
static __device__ __forceinline__ v2f fma2(v2f a, v2f b, v2f c) { return __builtin_elementwise_fma(a, b, c); }
static __device__ __forceinline__ v2f fmab(v2f a, float b, v2f c) { return __builtin_elementwise_fma(a, b2(b), c); }
static __device__ __forceinline__ v2f relu2(v2f a) { return __builtin_elementwise_max(a, b2(0.0f)); }

static __device__ __forceinline__ h2 bh(float s) { _Float16 h = (_Float16)s; return (h2){h, h}; }
static __device__ __forceinline__ h2 h2pack(v2f a) { return (h2){(_Float16)a.x, (_Float16)a.y}; }
static __device__ __forceinline__ h2 fmah(h2 a, h2 b, h2 c) { return __builtin_elementwise_fma(a, b, c); }
static __device__ __forceinline__ h2 reluh(h2 a) { return __builtin_elementwise_max(a, (h2){(_Float16)0.f, (_Float16)0.f}); }

// 4 rows/thread (two coalesced float4 streams). fp32 prologue per row-pair
// (gen MLP + affine precompute), packed-fp16 quadrature loop with 4
// independent chains, fp32 accumulation of f^2 via v_fma_mix. Rationale:
// CDNA vector fp16 == fp32 rate, so the win is slot amortization (prologue
// /4 rows) + ILP, not dtype rate.
__global__ __launch_bounds__(256) void monotone_h2x4(
    const float4* __restrict__ x4,
    const float* __restrict__ p_m0_wd, const float* __restrict__ p_m0_ws1,
    const float* __restrict__ p_m0_bs1, const float* __restrict__ p_m0_wl,
    const float* __restrict__ p_m0_bl,
    const float* __restrict__ p_m1_wd, const float* __restrict__ p_m1_ws0,
    const float* __restrict__ p_m1_bs0, const float* __restrict__ p_m1_ws1,
    const float* __restrict__ p_m1_bs1, const float* __restrict__ p_m1_wl,
    const float* __restrict__ p_m1_bl,
    const float* __restrict__ p_g0_b,
    const float* __restrict__ p_g1_ws0, const float* __restrict__ p_g1_bs0,
    const float* __restrict__ p_g1_ws1, const float* __restrict__ p_g1_bs1,
    const float* __restrict__ p_g1_wl, const float* __restrict__ p_g1_bl,
    float4* __restrict__ out4, int T)
{
    const int t = blockIdx.x * blockDim.x + threadIdx.x;
    if (t >= T) return;

    const float step = 1.0f / (float)NQ;

    // ---- uniform weights (fp32) ----
    float m0_wd[4], m0_ws1[16], m0_bs1[4], m0_wl[4], m0_bl;
    float m1_wd[4], m1_ws0[4], m1_bs0[4], m1_ws1[16], m1_bs1[4], m1_wl[4], m1_bl;
    float g0b;
    float g1_ws0[8], g1_bs0[4], g1_ws1[16], g1_bs1[4], g1_wl[4], g1_bl;

#pragma unroll
    for (int i = 0; i < 4; ++i) {
        m0_wd[i] = p_m0_wd[i];  m0_bs1[i] = p_m0_bs1[i];  m0_wl[i] = p_m0_wl[i];
        m1_wd[i] = p_m1_wd[i];  m1_ws0[i] = p_m1_ws0[i];  m1_bs0[i] = p_m1_bs0[i];
        m1_bs1[i] = p_m1_bs1[i]; m1_wl[i] = p_m1_wl[i];
        g1_bs0[i] = p_g1_bs0[i]; g1_bs1[i] = p_g1_bs1[i]; g1_wl[i] = p_g1_wl[i];
    }
#pragma unroll
    for (int i = 0; i < 16; ++i) { m0_ws1[i] = p_m0_ws1[i]; m1_ws1[i] = p_m1_ws1[i]; g1_ws1[i] = p_g1_ws1[i]; }
#pragma unroll
    for (int i = 0; i < 8; ++i) g1_ws0[i] = p_g1_ws0[i];
    m0_bl = p_m0_bl[0]; m1_bl = p_m1_bl[0]; g0b = p_g0_b[0]; g1_bl = p_g1_bl[0];

    // ---- load 4 rows (two coalesced streams) ----
    const float4 a = x4[t];
    const float4 b = x4[t + T];
    v2f x0P = {a.x, a.z}, x1P = {a.y, a.w};
    v2f x0Q = {b.x, b.z}, x1Q = {b.y, b.w};

    // ---- fp32 prologue per pair: gen MLP + affine precompute ----
    v2f gP, gQ;
    v2f cP[4], cQ[4], s1P[4], s1Q[4], ttP[4], ttQ[4];

    auto prologue = [&](v2f x0, v2f x1, v2f& g, v2f c[4], v2f s1[4], v2f tt[4]) {
        // gen MLP (2-4-4-1)
        v2f h0[4];
#pragma unroll
        for (int j = 0; j < 4; ++j)
            h0[j] = relu2(fmab(x1, g1_ws0[4 + j], fmab(x0, g1_ws0[j], b2(g1_bs0[j]))));
        v2f f = b2(g1_bl);
#pragma unroll
        for (int k = 0; k < 4; ++k) {
            v2f v = b2(g1_bs1[k]);
#pragma unroll
            for (int j = 0; j < 4; ++j) v = fmab(h0[j], g1_ws1[j * 4 + k], v);
            f = fmab(relu2(v), g1_wl[k], f);
        }
        g = f;
        // head 0: preact_k(q) = q*c_k + bs1_k
#pragma unroll
        for (int k = 0; k < 4; ++k) c[k] = b2(0.f);
#pragma unroll
        for (int h = 0; h < 4; ++h) {
            v2f rb = relu2(x0 * b2(m0_wd[h]));
#pragma unroll
            for (int k = 0; k < 4; ++k) c[k] = fmab(rb, m0_ws1[h * 4 + k], c[k]);
        }
        // head 1: u_h(q) = q*s1_h + tt_h
#pragma unroll
        for (int h = 0; h < 4; ++h) {
            s1[h] = x1 * b2(m1_wd[h]);
            tt[h] = fmab(x0, m1_ws0[h], b2(m1_bs0[h]));
        }
    };
    prologue(x0P, x1P, gP, cP, s1P, ttP);
    prologue(x0Q, x1Q, gQ, cQ, s1Q, ttQ);

    // ---- convert state + loop constants to packed fp16 ----
    h2 chP[4], shP[4], thP[4], chQ[4], shQ[4], thQ[4];
#pragma unroll
    for (int k = 0; k < 4; ++k) {
        chP[k] = h2pack(cP[k]);  shP[k] = h2pack(s1P[k]);  thP[k] = h2pack(ttP[k]);
        chQ[k] = h2pack(cQ[k]);  shQ[k] = h2pack(s1Q[k]);  thQ[k] = h2pack(ttQ[k]);
    }
    h2 m0_bs1h[4], m0_wlh[4], m1_ws1h[16], m1_bs1h[4], m1_wlh[4];
#pragma unroll
    for (int k = 0; k < 4; ++k) {
        m0_bs1h[k] = bh(m0_bs1[k]); m0_wlh[k] = bh(m0_wl[k]);
        m1_bs1h[k] = bh(m1_bs1[k]); m1_wlh[k] = bh(m1_wl[k]);
    }
#pragma unroll
    for (int i = 0; i < 16; ++i) m1_ws1h[i] = bh(m1_ws1[i]);
    const h2 m0_blh = bh(m0_bl);
    const h2 m1_blh = bh(m1_bl);

    // ---- quadrature loop: packed fp16, 4 chains, fp32 accum via fma_mix ----
    float a0P = 0.f, b0P = 0.f, a1P = 0.f, b1P = 0.f;
    float a0Q = 0.f, b0Q = 0.f, a1Q = 0.f, b1Q = 0.f;
    float qf = 0.0f;
#pragma unroll 2
    for (int qi = 0; qi < NQ; ++qi) {
        const _Float16 qh = (_Float16)qf;
        const h2 qq = (h2){qh, qh};

        // head 0, pair P and Q
        h2 f0P = m0_blh, f0Q = m0_blh;
#pragma unroll
        for (int k = 0; k < 4; ++k) {
            h2 vP = reluh(fmah(chP[k], qq, m0_bs1h[k]));
            h2 vQ = reluh(fmah(chQ[k], qq, m0_bs1h[k]));
            f0P = fmah(vP, m0_wlh[k], f0P);
            f0Q = fmah(vQ, m0_wlh[k], f0Q);
        }
        a0P = fmaf((float)f0P.x, (float)f0P.x, a0P);
        b0P = fmaf((float)f0P.y, (float)f0P.y, b0P);
        a0Q = fmaf((float)f0Q.x, (float)f0Q.x, a0Q);
        b0Q = fmaf((float)f0Q.y, (float)f0Q.y, b0Q);

        // head 1, pair P and Q
        h2 hP[4], hQ[4];
#pragma unroll
        for (int h = 0; h < 4; ++h) {
            hP[h] = reluh(fmah(shP[h], qq, thP[h]));
            hQ[h] = reluh(fmah(shQ[h], qq, thQ[h]));
        }
        h2 f1P = m1_blh, f1Q = m1_blh;
#pragma unroll
        for (int k = 0; k < 4; ++k) {
            h2 vP = fmah(hP[0], m1_ws1h[k], m1_bs1h[k]);
            h2 vQ = fmah(hQ[0], m1_ws1h[k], m1_bs1h[k]);
#pragma unroll
            for (int h = 1; h < 4; ++h) {
                vP = fmah(hP[h], m1_ws1h[h * 4 + k], vP);
                vQ = fmah(hQ[h], m1_ws1h[h * 4 + k], vQ);
            }
            f1P = fmah(reluh(vP), m1_wlh[k], f1P);
            f1Q = fmah(reluh(vQ), m1_wlh[k], f1Q);
        }
        a1P = fmaf((float)f1P.x, (float)f1P.x, a1P);
        b1P = fmaf((float)f1P.y, (float)f1P.y, b1P);
        a1Q = fmaf((float)f1Q.x, (float)f1Q.x, a1Q);
        b1Q = fmaf((float)f1Q.y, (float)f1Q.y, b1Q);

        qf += step;
    }

    // ---- epilogue (fp32) ----
    v2f acc0P = {a0P, b0P}, acc1P = {a1P, b1P};
    v2f acc0Q = {a0Q, b0Q}, acc1Q = {a1Q, b1Q};
    v2f y0P = (acc0P * b2(step)) * x0P + b2(g0b);
    v2f y1P = fma2(acc1P * b2(step), x1P, gP);
    v2f y0Q = (acc0Q * b2(step)) * x0Q + b2(g0b);
    v2f y1Q = fma2(acc1Q * b2(step), x1Q, gQ);

    const float4 oa = {y0P.x, y1P.x, y0P.y, y1P.y};
    const float4 ob = {y0Q.x, y1Q.x, y0Q.y, y1Q.y};
    out4[t] = oa;
    out4[t + T] = ob;
}

extern "C" void kernel_launch(void* const* d_in, const int* in_sizes, int n_in,
                              void* d_out, int out_size, void* d_ws, size_t ws_size,
                              hipStream_t stream) {
    const float* x       = (const float*)d_in[0];
    const float* m0_wd   = (const float*)d_in[1];
    const float* m0_ws1  = (const float*)d_in[2];
    const float* m0_bs1  = (const float*)d_in[3];
    const float* m0_wl   = (const float*)d_in[4];
    const float* m0_bl   = (const float*)d_in[5];
    const float* m1_wd   = (const float*)d_in[6];
    const float* m1_ws0  = (const float*)d_in[7];
    const float* m1_bs0  = (const float*)d_in[8];
    const float* m1_ws1  = (const float*)d_in[9];
    const float* m1_bs1  = (const float*)d_in[10];
    const float* m1_wl   = (const float*)d_in[11];
    const float* m1_bl   = (const float*)d_in[12];
    const float* g0_b    = (const float*)d_in[13];
    const float* g1_ws0  = (const float*)d_in[14];
    const float* g1_bs0  = (const float*)d_in[15];
    const float* g1_ws1  = (const float*)d_in[16];
    const float* g1_bs1  = (const float*)d_in[17];
    const float* g1_wl   = (const float*)d_in[18];
    const float* g1_bl   = (const float*)d_in[19];
    float* out = (float*)d_out;

    const int nrows = in_sizes[0] / 2;   // 1048576 (divisible by 4)
    const int T     = nrows / 4;         // 4 rows per thread, two streams
    const int threads = 256;
    const int blocks  = (T + threads - 1) / threads;

    hipLaunchKernelGGL(monotone_h2x4, dim3(blocks), dim3(threads), 0, stream,
                       (const float4*)x, m0_wd, m0_ws1, m0_bs1, m0_wl, m0_bl,
                       m1_wd, m1_ws0, m1_bs0, m1_ws1, m1_bs1, m1_wl, m1_bl,
                       g0_b, g1_ws0, g1_bs0, g1_ws1, g1_bs1, g1_wl, g1_bl,
                       (float4*)out, T);
}